// Round 3
// baseline (354.609 us; speedup 1.0000x reference)
//
#include <hip/hip_runtime.h>
#include <hip/hip_cooperative_groups.h>
#include <cstdint>

namespace cg = cooperative_groups;

using short8 = __attribute__((ext_vector_type(8))) short;
using f32x4  = __attribute__((ext_vector_type(4))) float;

#define NBLK 640

__device__ __forceinline__ uint16_t f2bf(float x) {
    uint32_t u = __float_as_uint(x);
    uint32_t r = (u + 0x7FFFu + ((u >> 16) & 1u)) >> 16;
    return (uint16_t)r;
}
__device__ __forceinline__ int fdiv7(int a) {
    int q = a / 7;
    if ((a % 7 != 0) && (a < 0)) q--;
    return q;
}

// Single cooperative kernel, 3 phases separated by grid.sync():
//  A: blocks [0,5) ROI decode | [5,37) cfeats->bf16 | [37,175) small transposes |
//     [175,591) W1 -> fragment-ready bf16 W1f
//  B: Q[b][bin][xy][o] = cfb[b] x W1f[bin]   (1274 virtual blocks, grid-stride)
//  C: per-ROI gather-sum over Q + fused MLP head (1250 virtual blocks)
__global__ void __launch_bounds__(256, 3)
k_all(const float* __restrict__ regcls,
      const float* __restrict__ wan,  const float* __restrict__ han,
      const float* __restrict__ xan,  const float* __restrict__ yan,
      const float* __restrict__ cf,   const float* __restrict__ w1,
      const float* __restrict__ w2,   const float* __restrict__ w3,
      const float* __restrict__ w4,
      const float* __restrict__ b1,   const float* __restrict__ b2,
      const float* __restrict__ b3,   const float* __restrict__ b4,
      int8_t* __restrict__ cells, uint16_t* __restrict__ cfb,
      uint16_t* __restrict__ w1f, float* __restrict__ w2t,
      float* __restrict__ w34t,  float* __restrict__ Q,
      float* __restrict__ out) {
    // LDS union: phase A w1f-transpose 51,456 B | phase B B-frags 16 KB | phase C z1/z2
    __shared__ __align__(16) char smraw[51456];
    float* smf = (float*)smraw;
    uint4* bs  = (uint4*)smraw;
    float* z1  = (float*)smraw;           // 200 floats
    float* z2  = (float*)(smraw + 800);   // 100 floats

    cg::grid_group grid = cg::this_grid();
    const int t   = threadIdx.x;
    const int blk = blockIdx.x;

    // ================= phase A =================
    if (blk < 5) {
        int r = blk * 256 + t;
        if (r < 1250) {
            int b = r / 625, n = r - b * 625;
            const float* rc = regcls + b * 3125 + n;
            float t0 = rc[0], t1 = rc[625], t2 = rc[1250], t3 = rc[1875];
            float wa = wan[n], ha = han[n], xa = xan[n], ya = yan[n];
            float wr = expf(t2) * wa, hr = expf(t3) * ha;
            float xr = t0 * wa + xa, yr = t1 * ha + ya;
            float xis = xr - wr * 0.5f, yis = yr - hr * 0.5f;
            float xfs = xr + wr * 0.5f, yfs = yr + hr * 0.5f;
            bool valid = (xis < 296.f) && (yis < 296.f) && (xfs >= 0.f) && (yfs >= 0.f);
            int c0 = (int)floorf(fmaxf(xis, 0.f));
            int c1 = (int)floorf(fmaxf(yis, 0.f));
            int c2 = (int)fminf(ceilf(xfs), 295.f);
            int c3 = (int)fmaxf(ceilf(yfs), 295.f);
            const int  XL1[17]    = {294,292,146,144,142,71,69,67,65,32,30,28,26,13,11,9,7};
            const bool ISCONV[17] = {1,1,0,1,1,0,1,1,1,0,1,1,1,0,1,1,1};
            #pragma unroll
            for (int i = 0; i < 17; i++) {
                if (ISCONV[i]) {
                    c0 = max(c0 - 1, 0); c1 = max(c1 - 1, 0);
                    c2 = min(c2, XL1[i] - 1); c3 = min(c3, XL1[i] - 1);
                } else {
                    c0 >>= 1; c1 >>= 1; c2 >>= 1; c3 >>= 1;
                }
            }
            int xi = c0, yi = c1, xf = c2, yf = c3;
            int wx = xf + 1 - xi, wy = yf + 1 - yi;
            int bx[8], by[8];
            #pragma unroll
            for (int i = 0; i < 8; i++) { bx[i] = xi + fdiv7(i * wx); by[i] = yi + fdiv7(i * wy); }
            int8_t* cr = cells + r * 64;
            #pragma unroll
            for (int i = 0; i < 7; i++)
                #pragma unroll
                for (int j = 0; j < 7; j++) {
                    bool ne = valid && (bx[i + 1] > bx[i]) && (by[j + 1] > by[j]);
                    cr[i * 7 + j] = ne ? (int8_t)(bx[i] * 7 + by[j]) : (int8_t)(-1);
                }
        }
    } else if (blk < 37) {
        int g = (blk - 5) * 256 + t;          // 8192 threads
        int b = g >> 12;
        int xy = (g >> 6) & 63;
        int c0 = (g & 63) * 8;
        uint32_t pk[4];
        if (xy < 49) {
            #pragma unroll
            for (int h = 0; h < 4; h++) {
                uint16_t lo = f2bf(cf[(b * 512 + c0 + 2 * h) * 49 + xy]);
                uint16_t hi = f2bf(cf[(b * 512 + c0 + 2 * h + 1) * 49 + xy]);
                pk[h] = (uint32_t)lo | ((uint32_t)hi << 16);
            }
        } else {
            pk[0] = pk[1] = pk[2] = pk[3] = 0;
        }
        ((uint4*)cfb)[(b * 64 + xy) * 64 + (g & 63)] = make_uint4(pk[0], pk[1], pk[2], pk[3]);
    } else if (blk < 175) {
        int g = (blk - 37) * 256 + t;
        if (g < 200 * 128) {
            int k = g >> 7, o = g & 127;
            w2t[g] = (o < 100) ? w2[o * 200 + k] : 0.f;
        }
        int u = g - 200 * 128;
        if (u >= 0 && u < 100 * 96) {
            int k = u / 96, o = u - k * 96;
            float v = 0.f;
            if (o < 17) v = w3[o * 100 + k];
            else if (o < 85) v = w4[(o - 17) * 100 + k];
            w34t[u] = v;
        }
    } else if (blk < 591) {
        int idx = blk - 175;                 // 0..415
        int nt = idx % 13, ct = idx / 13;
        int kbase = ct * 784;
        #pragma unroll 4
        for (int r = 0; r < 16; r++) {
            int o = nt * 16 + r;
            if (t < 196) {
                float4 v = make_float4(0.f, 0.f, 0.f, 0.f);
                if (o < 200) v = ((const float4*)(w1 + (size_t)o * 25088 + kbase))[t];
                *(float4*)&smf[r * 804 + 4 * t] = v;
            }
        }
        __syncthreads();
        int kc = ct >> 1;
        int q0 = (ct & 1) * 2;
        int lsub = t & 31;
        int l = q0 * 16 + lsub;
        int rrow = lsub & 15;
        int clbase = (lsub >> 4) * 8;
        for (int binb = 0; binb < 49; binb += 8) {
            int bin = binb + (t >> 5);
            if (bin < 49) {
                uint32_t pk[4];
                #pragma unroll
                for (int h = 0; h < 4; h++) {
                    uint16_t lo = f2bf(smf[rrow * 804 + (clbase + 2 * h) * 49 + bin]);
                    uint16_t hi = f2bf(smf[rrow * 804 + (clbase + 2 * h + 1) * 49 + bin]);
                    pk[h] = (uint32_t)lo | ((uint32_t)hi << 16);
                }
                ((uint4*)w1f)[((bin * 16 + kc) * 13 + nt) * 64 + l] =
                    make_uint4(pk[0], pk[1], pk[2], pk[3]);
            }
        }
    }

    grid.sync();

    // ================= phase B: Q-GEMM =================
    for (int vb = blk; vb < 1274; vb += NBLK) {
        int bin = vb % 49;
        int rest = vb / 49;
        int nt = rest % 13, b = rest / 13;
        const uint4* bw = (const uint4*)w1f + (bin * 208 + nt) * 64;
        for (int i = t; i < 16 * 64; i += 256) {
            int kc = i >> 6, l = i & 63;
            bs[i] = bw[kc * 832 + l];
        }
        __syncthreads();
        int w = t >> 6, l = t & 63;
        int r16 = l & 15, quad = l >> 4;
        const uint4* ap = (const uint4*)cfb + (b * 64 + w * 16 + r16) * 64 + quad;
        f32x4 acc = {0.f, 0.f, 0.f, 0.f};
        #pragma unroll
        for (int kc = 0; kc < 16; kc++) {
            uint4 av = ap[kc * 4];
            uint4 bv = bs[kc * 64 + l];
            short8 a8 = __builtin_bit_cast(short8, av);
            short8 b8 = __builtin_bit_cast(short8, bv);
            acc = __builtin_amdgcn_mfma_f32_16x16x32_bf16(a8, b8, acc, 0, 0, 0);
        }
        int o = nt * 16 + r16;
        int xybase = w * 16 + quad * 4;
        float* qb = Q + ((size_t)(b * 49 + bin) * 49) * 208 + o;
        #pragma unroll
        for (int reg = 0; reg < 4; reg++) {
            int xy = xybase + reg;
            if (xy < 49) qb[xy * 208] = acc[reg];
        }
        __syncthreads();   // LDS reuse across grid-stride iterations
    }

    grid.sync();

    // ================= phase C: gather + MLP head =================
    for (int vb = blk; vb < 1250; vb += NBLK) {
        int b = vb / 625, n = vb - b * 625;
        const int8_t* cr = cells + vb * 64;
        float s = 0.f;
        if (t < 208) {
            const float* qb = Q + (size_t)(b * 49) * 49 * 208 + t;
            for (int bin = 0; bin < 49; bin++) {
                int cv = cr[bin];
                if (cv >= 0) s += qb[(bin * 49 + cv) * 208];
            }
        }
        if (t < 200) z1[t] = fmaxf(s + b1[t], 0.f);
        __syncthreads();
        if (t < 100) {
            float a = b2[t];
            #pragma unroll 4
            for (int k = 0; k < 200; k++) a += z1[k] * w2t[k * 128 + t];
            z2[t] = fmaxf(a, 0.f);
        }
        __syncthreads();
        if (t < 85) {
            float a = (t < 17) ? b3[t] : b4[t - 17];
            #pragma unroll 4
            for (int k = 0; k < 100; k++) a += z2[k] * w34t[k * 96 + t];
            if (t < 17) {
                out[b * 10625 + n * 17 + t] = a;
            } else {
                int q = (t - 17) / 17, kk = (t - 17) - q * 17;
                out[21250 + b * 42500 + q * 10625 + n * 17 + kk] = a;
            }
        }
        __syncthreads();   // z1/z2 reuse across grid-stride iterations
    }
}

extern "C" void kernel_launch(void* const* d_in, const int* in_sizes, int n_in,
                              void* d_out, int out_size, void* d_ws, size_t ws_size,
                              hipStream_t stream) {
    const float* cfeats = (const float*)d_in[0];
    const float* regcls = (const float*)d_in[1];
    const float* wan    = (const float*)d_in[2];
    const float* han    = (const float*)d_in[3];
    const float* xan    = (const float*)d_in[4];
    const float* yan    = (const float*)d_in[5];
    const float* w1     = (const float*)d_in[6];
    const float* b1     = (const float*)d_in[7];
    const float* w2     = (const float*)d_in[8];
    const float* b2     = (const float*)d_in[9];
    const float* w3     = (const float*)d_in[10];
    const float* b3     = (const float*)d_in[11];
    const float* w4     = (const float*)d_in[12];
    const float* b4     = (const float*)d_in[13];

    char* ws = (char*)d_ws;
    int8_t*   cells = (int8_t*)ws;                    //     80,000 B
    uint16_t* cfb   = (uint16_t*)(ws + 80000);        //    131,072 B
    uint16_t* w1f   = (uint16_t*)(ws + 211072);       // 10,436,608 B
    float*    Q     = (float*)(ws + 10647680);        //  3,995,264 B
    float*    w2t   = (float*)(ws + 14642944);        //    102,400 B
    float*    w34t  = (float*)(ws + 14745344);        //     38,400 B
    float*    out   = (float*)d_out;

    void* args[] = {
        (void*)&regcls, (void*)&wan, (void*)&han, (void*)&xan, (void*)&yan,
        (void*)&cfeats, (void*)&w1,  (void*)&w2,  (void*)&w3,  (void*)&w4,
        (void*)&b1, (void*)&b2, (void*)&b3, (void*)&b4,
        (void*)&cells, (void*)&cfb, (void*)&w1f, (void*)&w2t, (void*)&w34t,
        (void*)&Q, (void*)&out
    };
    hipLaunchCooperativeKernel((void*)k_all, dim3(NBLK), dim3(256), args, 0, stream);
}

// Round 4
// 145.193 us; speedup vs baseline: 2.4423x; 2.4423x over previous
//
#include <hip/hip_runtime.h>
#include <cstdint>

using short8 = __attribute__((ext_vector_type(8))) short;
using f32x4  = __attribute__((ext_vector_type(4))) float;

__device__ __forceinline__ uint16_t f2bf(float x) {
    uint32_t u = __float_as_uint(x);
    uint32_t r = (u + 0x7FFFu + ((u >> 16) & 1u)) >> 16;
    return (uint16_t)r;
}
__device__ __forceinline__ int fdiv7(int a) {
    int q = a / 7;
    if ((a % 7 != 0) && (a < 0)) q--;
    return q;
}

// ---------------- merged prep: decode | cfb | wsmall | w1f ----------------
__global__ void __launch_bounds__(256) k_prep(const float* __restrict__ regcls,
                                              const float* __restrict__ wan,
                                              const float* __restrict__ han,
                                              const float* __restrict__ xan,
                                              const float* __restrict__ yan,
                                              const float* __restrict__ cf,
                                              const float* __restrict__ w1,
                                              const float* __restrict__ w2,
                                              const float* __restrict__ w3,
                                              const float* __restrict__ w4,
                                              int8_t* __restrict__ cells,
                                              uint16_t* __restrict__ cfb,
                                              uint16_t* __restrict__ w1f,
                                              float* __restrict__ w2t,
                                              float* __restrict__ w34t) {
    __shared__ float lds[16 * 804];   // 51,456 B (w1f branch only)
    int blk = blockIdx.x;
    int t = threadIdx.x;

    if (blk < 5) {
        // ---- ROI decode ----
        int r = blk * 256 + t;
        if (r >= 1250) return;
        int b = r / 625, n = r - b * 625;
        const float* rc = regcls + b * 3125 + n;
        float t0 = rc[0], t1 = rc[625], t2 = rc[1250], t3 = rc[1875];
        float wa = wan[n], ha = han[n], xa = xan[n], ya = yan[n];
        float wr = expf(t2) * wa, hr = expf(t3) * ha;
        float xr = t0 * wa + xa, yr = t1 * ha + ya;
        float xis = xr - wr * 0.5f, yis = yr - hr * 0.5f;
        float xfs = xr + wr * 0.5f, yfs = yr + hr * 0.5f;
        bool valid = (xis < 296.f) && (yis < 296.f) && (xfs >= 0.f) && (yfs >= 0.f);
        int c0 = (int)floorf(fmaxf(xis, 0.f));
        int c1 = (int)floorf(fmaxf(yis, 0.f));
        int c2 = (int)fminf(ceilf(xfs), 295.f);
        int c3 = (int)fmaxf(ceilf(yfs), 295.f);
        const int  XL1[17]    = {294,292,146,144,142,71,69,67,65,32,30,28,26,13,11,9,7};
        const bool ISCONV[17] = {1,1,0,1,1,0,1,1,1,0,1,1,1,0,1,1,1};
        #pragma unroll
        for (int i = 0; i < 17; i++) {
            if (ISCONV[i]) {
                c0 = max(c0 - 1, 0); c1 = max(c1 - 1, 0);
                c2 = min(c2, XL1[i] - 1); c3 = min(c3, XL1[i] - 1);
            } else {
                c0 >>= 1; c1 >>= 1; c2 >>= 1; c3 >>= 1;
            }
        }
        int xi = c0, yi = c1, xf = c2, yf = c3;
        int wx = xf + 1 - xi, wy = yf + 1 - yi;
        int bx[8], by[8];
        #pragma unroll
        for (int i = 0; i < 8; i++) { bx[i] = xi + fdiv7(i * wx); by[i] = yi + fdiv7(i * wy); }
        int8_t* cr = cells + r * 64;
        #pragma unroll
        for (int i = 0; i < 7; i++)
            #pragma unroll
            for (int j = 0; j < 7; j++) {
                bool ne = valid && (bx[i + 1] > bx[i]) && (by[j + 1] > by[j]);
                cr[i * 7 + j] = ne ? (int8_t)(bx[i] * 7 + by[j]) : (int8_t)(-1);
            }
    } else if (blk < 37) {
        // ---- cfeats -> bf16 [b][xy pad64][c 512] ----
        int g = (blk - 5) * 256 + t;          // 8192 threads
        int b = g >> 12;
        int xy = (g >> 6) & 63;
        int c0 = (g & 63) * 8;
        uint32_t pk[4];
        if (xy < 49) {
            #pragma unroll
            for (int h = 0; h < 4; h++) {
                uint16_t lo = f2bf(cf[(b * 512 + c0 + 2 * h) * 49 + xy]);
                uint16_t hi = f2bf(cf[(b * 512 + c0 + 2 * h + 1) * 49 + xy]);
                pk[h] = (uint32_t)lo | ((uint32_t)hi << 16);
            }
        } else {
            pk[0] = pk[1] = pk[2] = pk[3] = 0;
        }
        ((uint4*)cfb)[(b * 64 + xy) * 64 + (g & 63)] = make_uint4(pk[0], pk[1], pk[2], pk[3]);
    } else if (blk < 175) {
        // ---- small weight transposes ----
        int g = (blk - 37) * 256 + t;
        if (g < 200 * 128) {
            int k = g >> 7, o = g & 127;
            w2t[g] = (o < 100) ? w2[o * 200 + k] : 0.f;
        }
        int u = g - 200 * 128;
        if (u >= 0 && u < 100 * 96) {
            int k = u / 96, o = u - k * 96;
            float v = 0.f;
            if (o < 17) v = w3[o * 100 + k];
            else if (o < 85) v = w4[(o - 17) * 100 + k];
            w34t[u] = v;
        }
    } else {
        // ---- W1 -> fragment-ready bf16 W1f ----
        int idx = blk - 175;                 // 0..415
        int nt = idx % 13, ct = idx / 13;    // nt: o-tile of 16; ct: c-tile of 16
        int kbase = ct * 784;
        #pragma unroll 4
        for (int r = 0; r < 16; r++) {
            int o = nt * 16 + r;
            if (t < 196) {
                float4 v = make_float4(0.f, 0.f, 0.f, 0.f);
                if (o < 200) v = ((const float4*)(w1 + (size_t)o * 25088 + kbase))[t];
                *(float4*)&lds[r * 804 + 4 * t] = v;
            }
        }
        __syncthreads();
        int kc = ct >> 1;
        int q0 = (ct & 1) * 2;
        int lsub = t & 31;
        int l = q0 * 16 + lsub;              // lane within MFMA B-frag
        int rrow = lsub & 15;                // o - nt*16
        int clbase = (lsub >> 4) * 8;        // c offset within this 16-wide c-tile
        for (int binb = 0; binb < 49; binb += 8) {
            int bin = binb + (t >> 5);
            if (bin < 49) {
                uint32_t pk[4];
                #pragma unroll
                for (int h = 0; h < 4; h++) {
                    uint16_t lo = f2bf(lds[rrow * 804 + (clbase + 2 * h) * 49 + bin]);
                    uint16_t hi = f2bf(lds[rrow * 804 + (clbase + 2 * h + 1) * 49 + bin]);
                    pk[h] = (uint32_t)lo | ((uint32_t)hi << 16);
                }
                ((uint4*)w1f)[((bin * 16 + kc) * 13 + nt) * 64 + l] =
                    make_uint4(pk[0], pk[1], pk[2], pk[3]);
            }
        }
    }
}

// ---------------- G: Q[b][bin][xy 49][o 208] = cfb[b] x W1f[bin]  (bf16 MFMA) ----------------
// Both batches per block: B-frags staged once, reused for b=0,1.
__global__ void __launch_bounds__(256) k_qgemm(const uint16_t* __restrict__ cfb,
                                               const uint16_t* __restrict__ w1f,
                                               float* __restrict__ Q) {
    __shared__ uint4 bs[16 * 64];   // all 16 K-chunk B-frags for this (bin, nt): 16 KB
    int bin = blockIdx.x, nt = blockIdx.y;
    int t = threadIdx.x;
    const uint4* bw = (const uint4*)w1f + (bin * 208 + nt) * 64;   // 208 = 16*13
    for (int i = t; i < 16 * 64; i += 256) {
        int kc = i >> 6, l = i & 63;
        bs[i] = bw[kc * 832 + l];   // 832 = 13*64
    }
    __syncthreads();
    int w = t >> 6, l = t & 63;
    int r16 = l & 15, quad = l >> 4;
    int o = nt * 16 + r16;
    int xybase = w * 16 + quad * 4;
    #pragma unroll
    for (int b = 0; b < 2; b++) {
        const uint4* ap = (const uint4*)cfb + (b * 64 + w * 16 + r16) * 64 + quad;
        f32x4 acc = {0.f, 0.f, 0.f, 0.f};
        #pragma unroll
        for (int kc = 0; kc < 16; kc++) {
            uint4 av = ap[kc * 4];
            uint4 bv = bs[kc * 64 + l];
            short8 a8 = __builtin_bit_cast(short8, av);
            short8 b8 = __builtin_bit_cast(short8, bv);
            acc = __builtin_amdgcn_mfma_f32_16x16x32_bf16(a8, b8, acc, 0, 0, 0);
        }
        float* qb = Q + ((size_t)(b * 49 + bin) * 49) * 208 + o;
        #pragma unroll
        for (int reg = 0; reg < 4; reg++) {
            int xy = xybase + reg;
            if (xy < 49) qb[xy * 208] = acc[reg];
        }
    }
}

// ---------------- F: per-ROI gather-sum over Q + fused 3-layer MLP head ----------------
__global__ void __launch_bounds__(256) k_head(const int8_t* __restrict__ cells,
                                              const float* __restrict__ Q,
                                              const float* __restrict__ b1,
                                              const float* __restrict__ w2t,
                                              const float* __restrict__ b2,
                                              const float* __restrict__ w34t,
                                              const float* __restrict__ b3,
                                              const float* __restrict__ b4,
                                              float* __restrict__ out) {
    __shared__ float z1[200];
    __shared__ float z2[100];
    int r = blockIdx.x;
    int b = r / 625, n = r - b * 625;
    int t = threadIdx.x;
    const int8_t* cr = cells + r * 64;
    float s = 0.f;
    if (t < 208) {
        const float* qb = Q + (size_t)(b * 49) * 49 * 208 + t;
        // branchless, fully unrolled: 49 independent L2 loads in flight
        #pragma unroll
        for (int bin = 0; bin < 49; bin++) {
            int cv = (int)cr[bin];
            int idx = max(cv, 0);
            float m = (cv >= 0) ? 1.f : 0.f;
            s += m * qb[(bin * 49 + idx) * 208];
        }
    }
    if (t < 200) z1[t] = fmaxf(s + b1[t], 0.f);
    __syncthreads();
    if (t < 100) {
        float a = b2[t];
        #pragma unroll 4
        for (int k = 0; k < 200; k++) a += z1[k] * w2t[k * 128 + t];
        z2[t] = fmaxf(a, 0.f);
    }
    __syncthreads();
    if (t < 85) {
        float a = (t < 17) ? b3[t] : b4[t - 17];
        #pragma unroll 4
        for (int k = 0; k < 100; k++) a += z2[k] * w34t[k * 96 + t];
        if (t < 17) {
            out[b * 10625 + n * 17 + t] = a;
        } else {
            int q = (t - 17) / 17, kk = (t - 17) - q * 17;
            out[21250 + b * 42500 + q * 10625 + n * 17 + kk] = a;
        }
    }
}

extern "C" void kernel_launch(void* const* d_in, const int* in_sizes, int n_in,
                              void* d_out, int out_size, void* d_ws, size_t ws_size,
                              hipStream_t stream) {
    const float* cfeats = (const float*)d_in[0];
    const float* regcls = (const float*)d_in[1];
    const float* wan    = (const float*)d_in[2];
    const float* han    = (const float*)d_in[3];
    const float* xan    = (const float*)d_in[4];
    const float* yan    = (const float*)d_in[5];
    const float* w1     = (const float*)d_in[6];
    const float* b1     = (const float*)d_in[7];
    const float* w2     = (const float*)d_in[8];
    const float* b2     = (const float*)d_in[9];
    const float* w3     = (const float*)d_in[10];
    const float* b3     = (const float*)d_in[11];
    const float* w4     = (const float*)d_in[12];
    const float* b4     = (const float*)d_in[13];

    char* ws = (char*)d_ws;
    int8_t*   cells = (int8_t*)ws;                    //     80,000 B
    uint16_t* cfb   = (uint16_t*)(ws + 80000);        //    131,072 B
    uint16_t* w1f   = (uint16_t*)(ws + 211072);       // 10,436,608 B
    float*    Q     = (float*)(ws + 10647680);        //  3,995,264 B
    float*    w2t   = (float*)(ws + 14642944);        //    102,400 B
    float*    w34t  = (float*)(ws + 14745344);        //     38,400 B
    float*    out   = (float*)d_out;

    k_prep<<<dim3(591), dim3(256), 0, stream>>>(regcls, wan, han, xan, yan,
                                                cfeats, w1, w2, w3, w4,
                                                cells, cfb, w1f, w2t, w34t);
    k_qgemm<<<dim3(49, 13), dim3(256), 0, stream>>>(cfb, w1f, Q);
    k_head<<<dim3(1250), dim3(256), 0, stream>>>(cells, Q, b1, w2t, b2, w34t, b3, b4, out);
}